// Round 4
// baseline (206.701 us; speedup 1.0000x reference)
//
#include <hip/hip_runtime.h>

// ---------------------------------------------------------------------------
// CausalSelfAttention: fake-quant-i4 weights -> QKV gemm -> RMSNorm+RoPE+gain
// -> GQA causal flash attention -> out proj.  bf16 MFMA (16x16x32), fp32 acc.
// B=2 S=2048 H=16 KVH=4 D=64 DIM=1024.
// ---------------------------------------------------------------------------

typedef __bf16 bf16x8 __attribute__((ext_vector_type(8)));
typedef float  f32x4  __attribute__((ext_vector_type(4)));

__device__ __forceinline__ unsigned short f2bf(float f) {
  __bf16 h = (__bf16)f;                     // HW RNE cvt
  return __builtin_bit_cast(unsigned short, h);
}

// ---------------- fake_quant_i4 rows -> bf16 -------------------------------
__global__ void quant_rows(const float* __restrict__ src,
                           unsigned short* __restrict__ dst, int ncols) {
  int row = blockIdx.x;
  const float* s = src + (size_t)row * ncols;
  unsigned short* d = dst + (size_t)row * ncols;
  int t = threadIdx.x;
  float v[4]; float mx = 0.f;
#pragma unroll
  for (int i = 0; i < 4; i++) { v[i] = s[t + 256 * i]; mx = fmaxf(mx, fabsf(v[i])); }
#pragma unroll
  for (int m = 1; m < 64; m <<= 1) mx = fmaxf(mx, __shfl_xor(mx, m));
  __shared__ float smx[4];
  if ((t & 63) == 0) smx[t >> 6] = mx;
  __syncthreads();
  mx = fmaxf(fmaxf(smx[0], smx[1]), fmaxf(smx[2], smx[3]));
  mx = fmaxf(mx, 1e-8f);
  float scale = mx / 7.0f;                  // exact div to match jnp
#pragma unroll
  for (int i = 0; i < 4; i++) {
    float q = rintf(v[i] / scale);          // RNE == jnp.round
    q = fminf(fmaxf(q, -7.0f), 7.0f);
    d[t + 256 * i] = f2bf(q * scale);
  }
}

// ---------------- f32 -> bf16 ----------------------------------------------
__global__ void cvt_bf16(const float* __restrict__ src,
                         unsigned short* __restrict__ dst, int n) {
  int i = (blockIdx.x * 256 + threadIdx.x) * 4;
  if (i >= n) return;
  float4 f = *(const float4*)(src + i);
  ushort4 o;
  o.x = f2bf(f.x); o.y = f2bf(f.y); o.z = f2bf(f.z); o.w = f2bf(f.w);
  *(ushort4*)(dst + i) = o;
}

// ---------------- GEMM: C[M,N] = A[M,K] * B[N,K]^T  (bf16 in, f32 out) -----
#define GLDS(g, l)                                                            \
  __builtin_amdgcn_global_load_lds((const __attribute__((address_space(1))) void*)(g), \
                                   (__attribute__((address_space(3))) void*)(l), 16, 0, 0)

__global__ __launch_bounds__(256, 2) void gemm_bt(
    const unsigned short* __restrict__ A, const unsigned short* __restrict__ Bw,
    float* __restrict__ C, int N, int K, int nbn) {
  int bm = blockIdx.x / nbn, bn = blockIdx.x % nbn;
  int tid = threadIdx.x, w = tid >> 6, lane = tid & 63;
  int l15 = lane & 15, lh = lane >> 4;
  __shared__ __align__(16) unsigned short ldsA[128 * 64];
  __shared__ __align__(16) unsigned short ldsB[128 * 64];
  int wr = w >> 1, wc = w & 1;
  f32x4 zero = {0.f, 0.f, 0.f, 0.f};
  f32x4 acc[4][4];
#pragma unroll
  for (int i = 0; i < 4; i++)
#pragma unroll
    for (int j = 0; j < 4; j++) acc[i][j] = zero;

  int srow = lane >> 3, schunk = (lane & 7) ^ (lane >> 3);
  const unsigned short* gA0 = A  + (size_t)(bm * 128 + srow) * K + schunk * 8;
  const unsigned short* gB0 = Bw + (size_t)(bn * 128 + srow) * K + schunk * 8;

  int nk = K >> 6;
  for (int kt = 0; kt < nk; kt++) {
    int k0 = kt * 64;
#pragma unroll
    for (int it = 0; it < 4; it++) {
      int seg = w * 4 + it;
      GLDS(gA0 + (size_t)(seg * 8) * K + k0, (unsigned short*)ldsA + seg * 512);
      GLDS(gB0 + (size_t)(seg * 8) * K + k0, (unsigned short*)ldsB + seg * 512);
    }
    __syncthreads();
#pragma unroll
    for (int ks = 0; ks < 2; ks++) {
      bf16x8 af[4], bfr[4];
#pragma unroll
      for (int fm = 0; fm < 4; fm++) {
        int row = wr * 64 + fm * 16 + l15;
        int slot = (ks * 4 + lh) ^ (row & 7);
        af[fm] = *(const bf16x8*)(ldsA + row * 64 + slot * 8);
      }
#pragma unroll
      for (int fn = 0; fn < 4; fn++) {
        int row = wc * 64 + fn * 16 + l15;
        int slot = (ks * 4 + lh) ^ (row & 7);
        bfr[fn] = *(const bf16x8*)(ldsB + row * 64 + slot * 8);
      }
#pragma unroll
      for (int fm = 0; fm < 4; fm++)
#pragma unroll
        for (int fn = 0; fn < 4; fn++)
          acc[fm][fn] = __builtin_amdgcn_mfma_f32_16x16x32_bf16(af[fm], bfr[fn], acc[fm][fn], 0, 0, 0);
    }
    __syncthreads();
  }
#pragma unroll
  for (int fm = 0; fm < 4; fm++) {
    int r0 = bm * 128 + wr * 64 + fm * 16 + lh * 4;
#pragma unroll
    for (int fn = 0; fn < 4; fn++) {
      int c = bn * 128 + wc * 64 + fn * 16 + l15;
#pragma unroll
      for (int reg = 0; reg < 4; reg++)
        C[(size_t)(r0 + reg) * N + c] = acc[fm][fn][reg];
    }
  }
}

// ---------------- RMSNorm + RoPE + gain for Q,K ----------------------------
__global__ void postproc_qk(const float* __restrict__ qkv,
                            const float* __restrict__ gain,
                            unsigned short* __restrict__ qb,
                            unsigned short* __restrict__ kb) {
  int task = blockIdx.x * 4 + (threadIdx.x >> 6);
  int lane = threadIdx.x & 63;
  int token = task / 20, hh = task % 20;
  int b = token >> 11, s = token & 2047;
  bool isq = hh < 16;
  const float* src = qkv + (size_t)token * 1536 + (isq ? hh * 64 : 1024 + (hh - 16) * 64);
  float x = src[lane];
  float ss = x * x;
#pragma unroll
  for (int m = 1; m < 64; m <<= 1) ss += __shfl_xor(ss, m);
  x *= rsqrtf(ss * (1.0f / 64.0f) + 1.1920929e-7f);
  int i = lane & 31;
  float invf = expf(-0.28782313662425572f * (float)i);  // ln(10000)/32
  float ang = (float)s * invf;
  float c, sn;
  sincosf(ang, &sn, &c);
  float x1 = __shfl(x, i);
  float x2 = __shfl(x, i + 32);
  float out = (lane < 32) ? (x1 * c + x2 * sn) : (x2 * c - x1 * sn);
  if (isq) {
    out *= gain[hh];
    qb[((size_t)(b * 16 + hh) * 2048 + s) * 64 + lane] = f2bf(out);
  } else {
    kb[((size_t)(b * 4 + (hh - 16)) * 2048 + s) * 64 + lane] = f2bf(out);
  }
}

// ---------------- V transpose + kv-permute:  Vp[d][p] = V[kv0 + c(p)][d] ---
// per 128-kv block: position p holds original kv c(p) = ((p&7)<<4)|(p>>3).
// The SAME permutation is applied to P columns in attn, so P.V is invariant.
__global__ void v_transpose(const float* __restrict__ qkv,
                            unsigned short* __restrict__ vt) {
  int bid = blockIdx.x;
  int st = bid & 15, kvh = (bid >> 4) & 3, b = bid >> 6;
  __shared__ unsigned short tile[128][72];
  int t = threadIdx.x;
  int sl = t >> 1, d0 = (t & 1) * 32;
  const float* src = qkv + (size_t)(b * 2048 + st * 128 + sl) * 1536 + 1280 + kvh * 64 + d0;
#pragma unroll
  for (int j = 0; j < 32; j += 4) {
    float4 f = *(const float4*)(src + j);
    unsigned int lo = f2bf(f.x) | ((unsigned int)f2bf(f.y) << 16);
    unsigned int hi = f2bf(f.z) | ((unsigned int)f2bf(f.w) << 16);
    *(unsigned int*)&tile[sl][d0 + j]     = lo;
    *(unsigned int*)&tile[sl][d0 + j + 2] = hi;
  }
  __syncthreads();
  int d = t >> 2, pc = (t & 3) * 32;
  unsigned short* dst = vt + ((size_t)(b * 4 + kvh) * 64 + d) * 2048 + st * 128 + pc;
#pragma unroll
  for (int jo = 0; jo < 32; jo += 8) {
    ushort4 a, bb;
#pragma unroll
    for (int j = 0; j < 4; j++) {
      int p = pc + jo + j;
      int c = ((p & 7) << 4) | (p >> 3);
      ((unsigned short*)&a)[j] = tile[c][d];
    }
#pragma unroll
    for (int j = 4; j < 8; j++) {
      int p = pc + jo + j;
      int c = ((p & 7) << 4) | (p >> 3);
      ((unsigned short*)&bb)[j - 4] = tile[c][d];
    }
    *(ushort4*)(dst + jo)     = a;
    *(ushort4*)(dst + jo + 4) = bb;
  }
}

// ---------------- causal flash attention -----------------------------------
// 1 wave per block, 32 q-rows per wave; KV tile = 128; static softmax max
// (rows are RMS-normed: S <= 8*|gain|), so no online max/rescale at all.
#define PSTR 136  // P lds row stride (shorts): 272 B, 16B-aligned

template<bool MASK>
__device__ __forceinline__ void attn_tile(
    int kv0, int q0, int l15, int lh, float M2,
    const unsigned short* __restrict__ Kp, const unsigned short* __restrict__ Vp,
    const bf16x8 (&qf)[2][2], unsigned short* plds,
    float (&lsum)[2][4], f32x4 (&o)[2][4]) {
  const float K2 = 0.18033688011112042f;  // 0.125 * log2(e)
  f32x4 zero = {0.f, 0.f, 0.f, 0.f};
  f32x4 sc[2][8];
#pragma unroll
  for (int fm = 0; fm < 2; fm++)
#pragma unroll
    for (int fn = 0; fn < 8; fn++) sc[fm][fn] = zero;
  // --- QK^T ---
#pragma unroll
  for (int ks = 0; ks < 2; ks++) {
    bf16x8 kf[8];
#pragma unroll
    for (int fn = 0; fn < 8; fn++)
      kf[fn] = *(const bf16x8*)(Kp + (size_t)(kv0 + fn * 16 + l15) * 64 + ks * 32 + lh * 8);
#pragma unroll
    for (int fm = 0; fm < 2; fm++)
#pragma unroll
      for (int fn = 0; fn < 8; fn++)
        sc[fm][fn] = __builtin_amdgcn_mfma_f32_16x16x32_bf16(qf[fm][ks], kf[fn], sc[fm][fn], 0, 0, 0);
  }
  // --- V loads issued early; latency hides under softmax VALU ---
  bf16x8 vf[4][4];
#pragma unroll
  for (int ks2 = 0; ks2 < 4; ks2++)
#pragma unroll
    for (int fn = 0; fn < 4; fn++)
      vf[ks2][fn] = *(const bf16x8*)(Vp + (size_t)(fn * 16 + l15) * 2048 + kv0 + ks2 * 32 + lh * 8);
  // --- softmax with STATIC max bound M2 (exp2 domain); plain sum for l ---
#pragma unroll
  for (int fm = 0; fm < 2; fm++)
#pragma unroll
    for (int r = 0; r < 4; r++) {
      bf16x8 pk;
      float ls = 0.f;
#pragma unroll
      for (int fn = 0; fn < 8; fn++) {
        float s = __builtin_fmaf(sc[fm][fn][r], K2, -M2);
        if (MASK) {
          int col = kv0 + fn * 16 + l15;
          int row = q0 + fm * 16 + lh * 4 + r;
          if (col > row) s = -1e30f;
        }
        float p = __builtin_amdgcn_exp2f(s);
        ls += p;
        pk[fn] = (__bf16)p;
      }
      // permuted store: value (fn,l15) -> position l15*8+fn  (one b128)
      *(bf16x8*)(plds + (fm * 16 + lh * 4 + r) * PSTR + l15 * 8) = pk;
      lsum[fm][r] += ls;
    }
  asm volatile("s_waitcnt lgkmcnt(0)" ::: "memory");
  __builtin_amdgcn_sched_barrier(0);
  // --- P.V (kv-permuted on both sides) ---
#pragma unroll
  for (int ks2 = 0; ks2 < 4; ks2++) {
    bf16x8 pf[2];
#pragma unroll
    for (int fm = 0; fm < 2; fm++)
      pf[fm] = *(const bf16x8*)(plds + (fm * 16 + l15) * PSTR + ks2 * 32 + lh * 8);
#pragma unroll
    for (int fm = 0; fm < 2; fm++)
#pragma unroll
      for (int fn = 0; fn < 4; fn++)
        o[fm][fn] = __builtin_amdgcn_mfma_f32_16x16x32_bf16(pf[fm], vf[ks2][fn], o[fm][fn], 0, 0, 0);
  }
}

__global__ __launch_bounds__(64, 3) void attn_fwd(
    const unsigned short* __restrict__ qb, const unsigned short* __restrict__ kb,
    const unsigned short* __restrict__ vtb, const float* __restrict__ gain,
    unsigned short* __restrict__ ob) {
  int bid = blockIdx.x;           // 2048 blocks, heavy (high-qt) first
  int qtw = bid >> 5;             // 0..63
  int bh  = bid & 31;
  int qt  = 15 - (qtw >> 2);
  int w   = qtw & 3;
  int b = bh >> 4, h = bh & 15;
  int lane = threadIdx.x & 63;
  int l15 = lane & 15, lh = lane >> 4;
  int q0 = qt * 128 + w * 32;
  int kvh = h >> 2;
  const unsigned short* Q  = qb  + (size_t)(b * 16 + h) * (2048 * 64);
  const unsigned short* Kp = kb  + (size_t)(b * 4 + kvh) * (2048 * 64);
  const unsigned short* Vp = vtb + (size_t)(b * 4 + kvh) * (64 * 2048);

  // static softmax max (exp2 domain): S <= 8*|g| (+bf16 slack)
  float g = gain[h];
  float M2 = __builtin_fmaf(fabsf(g), 1.46f, 0.02f);

  bf16x8 qf[2][2];
#pragma unroll
  for (int fm = 0; fm < 2; fm++)
#pragma unroll
    for (int ks = 0; ks < 2; ks++)
      qf[fm][ks] = *(const bf16x8*)(Q + (q0 + fm * 16 + l15) * 64 + ks * 32 + lh * 8);

  f32x4 zero = {0.f, 0.f, 0.f, 0.f};
  f32x4 o[2][4];
  float lsum[2][4];
#pragma unroll
  for (int fm = 0; fm < 2; fm++)
#pragma unroll
    for (int r = 0; r < 4; r++) { lsum[fm][r] = 0.f; o[fm][r] = zero; }

  __shared__ __align__(16) unsigned short plds[32 * PSTR];

  int a = q0 >> 7;  // number of full (unmasked) 128-kv tiles
  for (int t = 0; t < a; t++)
    attn_tile<false>(t * 128, q0, l15, lh, M2, Kp, Vp, qf, plds, lsum, o);
  attn_tile<true>(a * 128, q0, l15, lh, M2, Kp, Vp, qf, plds, lsum, o);

#pragma unroll
  for (int fm = 0; fm < 2; fm++)
#pragma unroll
    for (int r = 0; r < 4; r++) {
      float l = lsum[fm][r];
      l += __shfl_xor(l, 1);
      l += __shfl_xor(l, 2);
      l += __shfl_xor(l, 4);
      l += __shfl_xor(l, 8);
      float inv = 1.0f / l;
      int row = q0 + fm * 16 + lh * 4 + r;
#pragma unroll
      for (int fn = 0; fn < 4; fn++) {
        int c = fn * 16 + l15;
        ob[(size_t)(b * 2048 + row) * 1024 + h * 64 + c] = f2bf(o[fm][fn][r] * inv);
      }
    }
}

// ---------------------------------------------------------------------------
extern "C" void kernel_launch(void* const* d_in, const int* in_sizes, int n_in,
                              void* d_out, int out_size, void* d_ws, size_t ws_size,
                              hipStream_t stream) {
  const float* x    = (const float*)d_in[0];
  const float* w_q  = (const float*)d_in[1];
  const float* w_k  = (const float*)d_in[2];
  const float* w_v  = (const float*)d_in[3];
  const float* w_p  = (const float*)d_in[4];
  const float* gain = (const float*)d_in[5];
  float* out = (float*)d_out;

  char* ws = (char*)d_ws;
  unsigned short* x_bf  = (unsigned short*)ws;                   //  8 MB
  unsigned short* wqkv  = (unsigned short*)(ws + (8u << 20));    //  3 MB
  unsigned short* wp    = (unsigned short*)(ws + (11u << 20));   //  2 MB
  float*          qkv   = (float*)(ws + (13u << 20));            // 24 MB
  unsigned short* qbuf  = (unsigned short*)(ws + (37u << 20));   //  8 MB
  unsigned short* kbuf  = (unsigned short*)(ws + (45u << 20));   //  2 MB
  unsigned short* vtbuf = (unsigned short*)(ws + (47u << 20));   //  2 MB
  unsigned short* aout  = (unsigned short*)(ws + (49u << 20));   //  8 MB

  quant_rows<<<1024, 256, 0, stream>>>(w_q, wqkv, 1024);
  quant_rows<<<256, 256, 0, stream>>>(w_k, wqkv + 1024 * 1024, 1024);
  quant_rows<<<256, 256, 0, stream>>>(w_v, wqkv + 1280 * 1024, 1024);
  quant_rows<<<1024, 256, 0, stream>>>(w_p, wp, 1024);
  cvt_bf16<<<4096, 256, 0, stream>>>(x, x_bf, 4194304);
  gemm_bt<<<32 * 12, 256, 0, stream>>>(x_bf, wqkv, qkv, 1536, 1024, 12);
  postproc_qk<<<20480, 256, 0, stream>>>(qkv, gain, qbuf, kbuf);
  v_transpose<<<128, 256, 0, stream>>>(qkv, vtbuf);
  attn_fwd<<<2048, 64, 0, stream>>>(qbuf, kbuf, vtbuf, gain, aout);
  gemm_bt<<<32 * 8, 256, 0, stream>>>(aout, wp, out, 1024, 1024, 8);
}

// Round 6
// 121.065 us; speedup vs baseline: 1.7074x; 1.7074x over previous
//
#include <hip/hip_runtime.h>

// ---------------------------------------------------------------------------
// CausalSelfAttention: fake-quant-i4 weights -> QKV gemm -> RMSNorm+RoPE+gain
// -> GQA causal flash attention -> out proj.  bf16 MFMA (16x16x32), fp32 acc.
// B=2 S=2048 H=16 KVH=4 D=64 DIM=1024.
// ---------------------------------------------------------------------------

typedef __bf16 bf16x8 __attribute__((ext_vector_type(8)));
typedef float  f32x4  __attribute__((ext_vector_type(4)));

__device__ __forceinline__ unsigned short f2bf(float f) {
  __bf16 h = (__bf16)f;                     // HW RNE cvt
  return __builtin_bit_cast(unsigned short, h);
}

// ---------------- fake_quant_i4 rows -> bf16 -------------------------------
__global__ void quant_rows(const float* __restrict__ src,
                           unsigned short* __restrict__ dst, int ncols) {
  int row = blockIdx.x;
  const float* s = src + (size_t)row * ncols;
  unsigned short* d = dst + (size_t)row * ncols;
  int t = threadIdx.x;
  float v[4]; float mx = 0.f;
#pragma unroll
  for (int i = 0; i < 4; i++) { v[i] = s[t + 256 * i]; mx = fmaxf(mx, fabsf(v[i])); }
#pragma unroll
  for (int m = 1; m < 64; m <<= 1) mx = fmaxf(mx, __shfl_xor(mx, m));
  __shared__ float smx[4];
  if ((t & 63) == 0) smx[t >> 6] = mx;
  __syncthreads();
  mx = fmaxf(fmaxf(smx[0], smx[1]), fmaxf(smx[2], smx[3]));
  mx = fmaxf(mx, 1e-8f);
  float scale = mx / 7.0f;                  // exact div to match jnp
#pragma unroll
  for (int i = 0; i < 4; i++) {
    float q = rintf(v[i] / scale);          // RNE == jnp.round
    q = fminf(fmaxf(q, -7.0f), 7.0f);
    d[t + 256 * i] = f2bf(q * scale);
  }
}

// ---------------- f32 -> bf16 ----------------------------------------------
__global__ void cvt_bf16(const float* __restrict__ src,
                         unsigned short* __restrict__ dst, int n) {
  int i = (blockIdx.x * 256 + threadIdx.x) * 4;
  if (i >= n) return;
  float4 f = *(const float4*)(src + i);
  ushort4 o;
  o.x = f2bf(f.x); o.y = f2bf(f.y); o.z = f2bf(f.z); o.w = f2bf(f.w);
  *(ushort4*)(dst + i) = o;
}

// ---------------- GEMM: C[M,N] = A[M,K] * B[N,K]^T  (bf16 in, f32 out) -----
#define GLDS(g, l)                                                            \
  __builtin_amdgcn_global_load_lds((const __attribute__((address_space(1))) void*)(g), \
                                   (__attribute__((address_space(3))) void*)(l), 16, 0, 0)

__global__ __launch_bounds__(256, 2) void gemm_bt(
    const unsigned short* __restrict__ A, const unsigned short* __restrict__ Bw,
    float* __restrict__ C, int N, int K, int nbn) {
  int bm = blockIdx.x / nbn, bn = blockIdx.x % nbn;
  int tid = threadIdx.x, w = tid >> 6, lane = tid & 63;
  int l15 = lane & 15, lh = lane >> 4;
  __shared__ __align__(16) unsigned short ldsA[128 * 64];
  __shared__ __align__(16) unsigned short ldsB[128 * 64];
  int wr = w >> 1, wc = w & 1;
  f32x4 zero = {0.f, 0.f, 0.f, 0.f};
  f32x4 acc[4][4];
#pragma unroll
  for (int i = 0; i < 4; i++)
#pragma unroll
    for (int j = 0; j < 4; j++) acc[i][j] = zero;

  int srow = lane >> 3, schunk = (lane & 7) ^ (lane >> 3);
  const unsigned short* gA0 = A  + (size_t)(bm * 128 + srow) * K + schunk * 8;
  const unsigned short* gB0 = Bw + (size_t)(bn * 128 + srow) * K + schunk * 8;

  int nk = K >> 6;
  for (int kt = 0; kt < nk; kt++) {
    int k0 = kt * 64;
#pragma unroll
    for (int it = 0; it < 4; it++) {
      int seg = w * 4 + it;
      GLDS(gA0 + (size_t)(seg * 8) * K + k0, (unsigned short*)ldsA + seg * 512);
      GLDS(gB0 + (size_t)(seg * 8) * K + k0, (unsigned short*)ldsB + seg * 512);
    }
    __syncthreads();
#pragma unroll
    for (int ks = 0; ks < 2; ks++) {
      bf16x8 af[4], bfr[4];
#pragma unroll
      for (int fm = 0; fm < 4; fm++) {
        int row = wr * 64 + fm * 16 + l15;
        int slot = (ks * 4 + lh) ^ (row & 7);
        af[fm] = *(const bf16x8*)(ldsA + row * 64 + slot * 8);
      }
#pragma unroll
      for (int fn = 0; fn < 4; fn++) {
        int row = wc * 64 + fn * 16 + l15;
        int slot = (ks * 4 + lh) ^ (row & 7);
        bfr[fn] = *(const bf16x8*)(ldsB + row * 64 + slot * 8);
      }
#pragma unroll
      for (int fm = 0; fm < 4; fm++)
#pragma unroll
        for (int fn = 0; fn < 4; fn++)
          acc[fm][fn] = __builtin_amdgcn_mfma_f32_16x16x32_bf16(af[fm], bfr[fn], acc[fm][fn], 0, 0, 0);
    }
    __syncthreads();
  }
#pragma unroll
  for (int fm = 0; fm < 4; fm++) {
    int r0 = bm * 128 + wr * 64 + fm * 16 + lh * 4;
#pragma unroll
    for (int fn = 0; fn < 4; fn++) {
      int c = bn * 128 + wc * 64 + fn * 16 + l15;
#pragma unroll
      for (int reg = 0; reg < 4; reg++)
        C[(size_t)(r0 + reg) * N + c] = acc[fm][fn][reg];
    }
  }
}

// ---------------- RMSNorm + RoPE + gain for Q,K ----------------------------
__global__ void postproc_qk(const float* __restrict__ qkv,
                            const float* __restrict__ gain,
                            unsigned short* __restrict__ qb,
                            unsigned short* __restrict__ kb) {
  int task = blockIdx.x * 4 + (threadIdx.x >> 6);
  int lane = threadIdx.x & 63;
  int token = task / 20, hh = task % 20;
  int b = token >> 11, s = token & 2047;
  bool isq = hh < 16;
  const float* src = qkv + (size_t)token * 1536 + (isq ? hh * 64 : 1024 + (hh - 16) * 64);
  float x = src[lane];
  float ss = x * x;
#pragma unroll
  for (int m = 1; m < 64; m <<= 1) ss += __shfl_xor(ss, m);
  x *= rsqrtf(ss * (1.0f / 64.0f) + 1.1920929e-7f);
  int i = lane & 31;
  float invf = expf(-0.28782313662425572f * (float)i);  // ln(10000)/32
  float ang = (float)s * invf;
  float c, sn;
  sincosf(ang, &sn, &c);
  float x1 = __shfl(x, i);
  float x2 = __shfl(x, i + 32);
  float out = (lane < 32) ? (x1 * c + x2 * sn) : (x2 * c - x1 * sn);
  if (isq) {
    out *= gain[hh];
    qb[((size_t)(b * 16 + hh) * 2048 + s) * 64 + lane] = f2bf(out);
  } else {
    kb[((size_t)(b * 4 + (hh - 16)) * 2048 + s) * 64 + lane] = f2bf(out);
  }
}

// ---------------- V transpose + kv-permute:  Vp[d][p] = V[kv0 + c(p)][d] ---
// per 128-kv block: position p holds original kv c(p) = ((p&7)<<4)|(p>>3).
// The SAME permutation is applied to P columns in attn, so P.V is invariant.
__global__ void v_transpose(const float* __restrict__ qkv,
                            unsigned short* __restrict__ vt) {
  int bid = blockIdx.x;
  int st = bid & 15, kvh = (bid >> 4) & 3, b = bid >> 6;
  __shared__ unsigned short tile[128][72];
  int t = threadIdx.x;
  int sl = t >> 1, d0 = (t & 1) * 32;
  const float* src = qkv + (size_t)(b * 2048 + st * 128 + sl) * 1536 + 1280 + kvh * 64 + d0;
#pragma unroll
  for (int j = 0; j < 32; j += 4) {
    float4 f = *(const float4*)(src + j);
    unsigned int lo = f2bf(f.x) | ((unsigned int)f2bf(f.y) << 16);
    unsigned int hi = f2bf(f.z) | ((unsigned int)f2bf(f.w) << 16);
    *(unsigned int*)&tile[sl][d0 + j]     = lo;
    *(unsigned int*)&tile[sl][d0 + j + 2] = hi;
  }
  __syncthreads();
  int d = t >> 2, pc = (t & 3) * 32;
  unsigned short* dst = vt + ((size_t)(b * 4 + kvh) * 64 + d) * 2048 + st * 128 + pc;
#pragma unroll
  for (int jo = 0; jo < 32; jo += 8) {
    ushort4 a, bb;
#pragma unroll
    for (int j = 0; j < 4; j++) {
      int p = pc + jo + j;
      int c = ((p & 7) << 4) | (p >> 3);
      ((unsigned short*)&a)[j] = tile[c][d];
    }
#pragma unroll
    for (int j = 4; j < 8; j++) {
      int p = pc + jo + j;
      int c = ((p & 7) << 4) | (p >> 3);
      ((unsigned short*)&bb)[j - 4] = tile[c][d];
    }
    *(ushort4*)(dst + jo)     = a;
    *(ushort4*)(dst + jo + 4) = bb;
  }
}

// ---------------- causal flash attention (4-wave cooperative) --------------
// block = (b, h, q-block of 128); 4 waves x 32 q-rows.  Per 128-kv tile the
// block stages K[128][64] and Vp[64][128] into LDS (global_load_lds, XOR
// both-sides swizzle), then each wave computes QK^T / static-max softmax /
// PV from LDS.  P per wave in LDS, PSTR=136 (>=128 cols + bank spread).
#define PSTR 136

template<bool MASK>
__device__ __forceinline__ void attn_tile(
    int kv0, int q0, int l15, int lh, float M2,
    const unsigned short* ldsK, const unsigned short* ldsV, unsigned short* pw,
    const bf16x8 (&qf)[2][2], float (&lsum)[2][4], f32x4 (&o)[2][4]) {
  const float K2 = 0.18033688011112042f;  // 0.125 * log2(e)
  f32x4 zero = {0.f, 0.f, 0.f, 0.f};
#pragma unroll
  for (int fm = 0; fm < 2; fm++) {
    f32x4 sc[8];
#pragma unroll
    for (int fn = 0; fn < 8; fn++) sc[fn] = zero;
#pragma unroll
    for (int ks = 0; ks < 2; ks++)
#pragma unroll
      for (int fh = 0; fh < 2; fh++) {
        bf16x8 kf[4];
#pragma unroll
        for (int j = 0; j < 4; j++) {
          int row = (fh * 4 + j) * 16 + l15;
          int slot = (ks * 4 + lh) ^ (row & 7);
          kf[j] = *(const bf16x8*)(ldsK + row * 64 + slot * 8);
        }
#pragma unroll
        for (int j = 0; j < 4; j++)
          sc[fh * 4 + j] = __builtin_amdgcn_mfma_f32_16x16x32_bf16(qf[fm][ks], kf[j], sc[fh * 4 + j], 0, 0, 0);
      }
#pragma unroll
    for (int r = 0; r < 4; r++) {
      bf16x8 pk;
      float ls = 0.f;
#pragma unroll
      for (int fn = 0; fn < 8; fn++) {
        float s = __builtin_fmaf(sc[fn][r], K2, -M2);
        if (MASK) {
          int col = kv0 + fn * 16 + l15;
          int row = q0 + fm * 16 + lh * 4 + r;
          if (col > row) s = -1e30f;
        }
        float p = __builtin_amdgcn_exp2f(s);
        ls += p;
        pk[fn] = (__bf16)p;
      }
      // permuted store: value (fn,l15) -> position l15*8+fn  (one b128)
      *(bf16x8*)(pw + (fm * 16 + lh * 4 + r) * PSTR + l15 * 8) = pk;
      lsum[fm][r] += ls;
    }
  }
  asm volatile("s_waitcnt lgkmcnt(0)" ::: "memory");
  __builtin_amdgcn_sched_barrier(0);
  // --- P.V (kv-permuted on both sides), V from LDS -------------------------
#pragma unroll
  for (int ks2 = 0; ks2 < 4; ks2++) {
    bf16x8 vf[4], pf[2];
#pragma unroll
    for (int fn = 0; fn < 4; fn++) {
      int row = fn * 16 + l15;
      int slot = (ks2 * 4 + lh) ^ (row & 7);
      vf[fn] = *(const bf16x8*)(ldsV + row * 128 + slot * 8);
    }
#pragma unroll
    for (int fm = 0; fm < 2; fm++)
      pf[fm] = *(const bf16x8*)(pw + (fm * 16 + l15) * PSTR + ks2 * 32 + lh * 8);
#pragma unroll
    for (int fm = 0; fm < 2; fm++)
#pragma unroll
      for (int fn = 0; fn < 4; fn++)
        o[fm][fn] = __builtin_amdgcn_mfma_f32_16x16x32_bf16(pf[fm], vf[fn], o[fm][fn], 0, 0, 0);
  }
}

__global__ __launch_bounds__(256, 2) void attn_fwd(
    const unsigned short* __restrict__ qbuf, const unsigned short* __restrict__ kb,
    const unsigned short* __restrict__ vtb, const float* __restrict__ gain,
    unsigned short* __restrict__ ob) {
  int bid = blockIdx.x;
  int qblk = 15 - (bid >> 5);     // heavy blocks dispatch first
  int bh = bid & 31;
  int b = bh >> 4, h = bh & 15;
  int tid = threadIdx.x;
  int w = tid >> 6, lane = tid & 63;
  int l15 = lane & 15, lh = lane >> 4;
  int q0 = qblk * 128 + w * 32;
  int kvh = h >> 2;
  const unsigned short* Q  = qbuf + (size_t)(b * 16 + h) * (2048 * 64);
  const unsigned short* Kg = kb   + (size_t)(b * 4 + kvh) * (2048 * 64);
  const unsigned short* Vg = vtb  + (size_t)(b * 4 + kvh) * (64 * 2048);

  __shared__ __align__(16) unsigned short ldsK[128 * 64];      // 16 KB
  __shared__ __align__(16) unsigned short ldsV[64 * 128];      // 16 KB
  __shared__ __align__(16) unsigned short plds[4][32 * PSTR];  // 34 KB
  unsigned short* pw = plds[w];

  float g = gain[h];
  float M2 = __builtin_fmaf(fabsf(g), 1.46f, 0.02f);  // static max bound

  bf16x8 qf[2][2];
#pragma unroll
  for (int fm = 0; fm < 2; fm++)
#pragma unroll
    for (int ks = 0; ks < 2; ks++)
      qf[fm][ks] = *(const bf16x8*)(Q + (q0 + fm * 16 + l15) * 64 + ks * 32 + lh * 8);

  f32x4 zero = {0.f, 0.f, 0.f, 0.f};
  f32x4 o[2][4];
  float lsum[2][4];
#pragma unroll
  for (int fm = 0; fm < 2; fm++)
#pragma unroll
    for (int r = 0; r < 4; r++) { lsum[fm][r] = 0.f; o[fm][r] = zero; }

  // staging lane geometry (16 segs per operand, 4 per wave)
  int krow = lane >> 3;                    // row within 8-row K segment
  int kchunk = (lane & 7) ^ (lane >> 3);   // pre-swizzled global chunk
  int vrow = lane >> 4;                    // row within 4-row V segment
  int full = (q0 + 1) >> 7;                // # fully-unmasked tiles for this wave
  int nt = qblk + 1;

  for (int t = 0; t < nt; t++) {
    int kv0 = t * 128;
#pragma unroll
    for (int it = 0; it < 4; it++) {
      int seg = w * 4 + it;
      GLDS(Kg + (size_t)(kv0 + seg * 8 + krow) * 64 + kchunk * 8,
           (unsigned short*)ldsK + seg * 512);
      int vr = seg * 4 + vrow;
      int vchunk = (lane & 15) ^ (vr & 7);
      GLDS(Vg + (size_t)vr * 2048 + kv0 + vchunk * 8,
           (unsigned short*)ldsV + seg * 512);
    }
    __syncthreads();
    if (t < full)
      attn_tile<false>(kv0, q0, l15, lh, M2, ldsK, ldsV, pw, qf, lsum, o);
    else if (kv0 <= q0 + 31)
      attn_tile<true>(kv0, q0, l15, lh, M2, ldsK, ldsV, pw, qf, lsum, o);
    __syncthreads();
  }

#pragma unroll
  for (int fm = 0; fm < 2; fm++)
#pragma unroll
    for (int r = 0; r < 4; r++) {
      float l = lsum[fm][r];
      l += __shfl_xor(l, 1);
      l += __shfl_xor(l, 2);
      l += __shfl_xor(l, 4);
      l += __shfl_xor(l, 8);
      float inv = 1.0f / l;
      int row = q0 + fm * 16 + lh * 4 + r;
#pragma unroll
      for (int fn = 0; fn < 4; fn++) {
        int c = fn * 16 + l15;
        ob[(size_t)(b * 2048 + row) * 1024 + h * 64 + c] = f2bf(o[fm][fn][r] * inv);
      }
    }
}

// ---------------------------------------------------------------------------
extern "C" void kernel_launch(void* const* d_in, const int* in_sizes, int n_in,
                              void* d_out, int out_size, void* d_ws, size_t ws_size,
                              hipStream_t stream) {
  const float* x    = (const float*)d_in[0];
  const float* w_q  = (const float*)d_in[1];
  const float* w_k  = (const float*)d_in[2];
  const float* w_v  = (const float*)d_in[3];
  const float* w_p  = (const float*)d_in[4];
  const float* gain = (const float*)d_in[5];
  float* out = (float*)d_out;

  char* ws = (char*)d_ws;
  unsigned short* x_bf  = (unsigned short*)ws;                   //  8 MB
  unsigned short* wqkv  = (unsigned short*)(ws + (8u << 20));    //  3 MB
  unsigned short* wp    = (unsigned short*)(ws + (11u << 20));   //  2 MB
  float*          qkv   = (float*)(ws + (13u << 20));            // 24 MB
  unsigned short* qbuf  = (unsigned short*)(ws + (37u << 20));   //  8 MB
  unsigned short* kbuf  = (unsigned short*)(ws + (45u << 20));   //  2 MB
  unsigned short* vtbuf = (unsigned short*)(ws + (47u << 20));   //  2 MB
  unsigned short* aout  = (unsigned short*)(ws + (49u << 20));   //  8 MB

  quant_rows<<<1024, 256, 0, stream>>>(w_q, wqkv, 1024);
  quant_rows<<<256, 256, 0, stream>>>(w_k, wqkv + 1024 * 1024, 1024);
  quant_rows<<<256, 256, 0, stream>>>(w_v, wqkv + 1280 * 1024, 1024);
  quant_rows<<<1024, 256, 0, stream>>>(w_p, wp, 1024);
  cvt_bf16<<<4096, 256, 0, stream>>>(x, x_bf, 4194304);
  gemm_bt<<<32 * 12, 256, 0, stream>>>(x_bf, wqkv, qkv, 1536, 1024, 12);
  postproc_qk<<<20480, 256, 0, stream>>>(qkv, gain, qbuf, kbuf);
  v_transpose<<<128, 256, 0, stream>>>(qkv, vtbuf);
  attn_fwd<<<512, 256, 0, stream>>>(qbuf, kbuf, vtbuf, gain, aout);
  gemm_bt<<<32 * 8, 256, 0, stream>>>(aout, wp, out, 1024, 1024, 8);
}